// Round 1
// baseline (483.767 us; speedup 1.0000x reference)
//
#include <hip/hip_runtime.h>

#define T_DIM 4096
#define N_DIM 128
#define D_DIM 128
#define CHUNK 256
#define NCHUNK (T_DIM / CHUNK)   // 16
#define NEGE (-1.0e9f)

// ---------------------------------------------------------------------------
// K1: energy[n,t] = dot(key[t,n,:], q[n,:]); masked t -> NEGE (key not read).
// Grid: N_DIM * NCHUNK blocks, 256 threads. Writes raw energy into att region
// of d_out and per-(n,chunk) max into ws.
// ---------------------------------------------------------------------------
__global__ __launch_bounds__(256) void energy_kernel(
    const float* __restrict__ q,      // (N,D)
    const float* __restrict__ key,    // (T,N,D)
    const int*   __restrict__ lens,   // (N)
    float*       __restrict__ att,    // (N,T)
    float*       __restrict__ blockmax) // (N,NCHUNK)
{
    const int b    = blockIdx.x;
    const int n    = b & (N_DIM - 1);
    const int c    = b >> 7;            // b / N_DIM
    const int t0   = c * CHUNK;
    const int len  = lens[n];
    const int tid  = threadIdx.x;

    // Fast path: whole chunk masked -> write NEGE, no key reads.
    if (t0 >= len) {
        att[(size_t)n * T_DIM + t0 + tid] = NEGE;
        if (tid == 0) blockmax[n * NCHUNK + c] = NEGE;
        return;
    }

    const int wave = tid >> 6;          // 0..3
    const int lane = tid & 63;
    const int half = lane >> 5;         // 0/1 (each half owns one t)
    const int l32  = lane & 31;

    // q fragment: float4 at d = l32*4 (covers all 128 d across 32 lanes)
    const float4 qv = *(const float4*)(q + n * D_DIM + l32 * 4);

    float lmax = NEGE;

    // Wave handles t pairs: t = t0 + wave*2 + i*8 + half, i in [0,32)
    #pragma unroll 4
    for (int i = 0; i < CHUNK / 8; ++i) {
        const int t = t0 + wave * 2 + i * 8 + half;
        float e;
        if (t < len) {   // uniform per 32-lane half
            const float4 kv = *(const float4*)(key + (size_t)t * (N_DIM * D_DIM)
                                               + n * D_DIM + l32 * 4);
            float p = kv.x * qv.x + kv.y * qv.y + kv.z * qv.z + kv.w * qv.w;
            p += __shfl_xor(p, 1);
            p += __shfl_xor(p, 2);
            p += __shfl_xor(p, 4);
            p += __shfl_xor(p, 8);
            p += __shfl_xor(p, 16);
            e = p;
        } else {
            e = NEGE;
        }
        if (l32 == 0) att[(size_t)n * T_DIM + t] = e;
        lmax = fmaxf(lmax, e);
    }

    // lmax is uniform within each half; combine halves, then across waves.
    lmax = fmaxf(lmax, __shfl_xor(lmax, 32));
    __shared__ float smax[4];
    if (lane == 0) smax[wave] = lmax;
    __syncthreads();
    if (tid == 0) {
        blockmax[n * NCHUNK + c] =
            fmaxf(fmaxf(smax[0], smax[1]), fmaxf(smax[2], smax[3]));
    }
}

// ---------------------------------------------------------------------------
// K2: per-row softmax. One block per n, 256 threads; 16 floats/thread kept in
// registers between the exp pass and the normalize pass.
// ---------------------------------------------------------------------------
__global__ __launch_bounds__(256) void softmax_kernel(
    float* __restrict__ att,              // (N,T)
    const float* __restrict__ blockmax)   // (N,NCHUNK)
{
    const int n   = blockIdx.x;
    const int tid = threadIdx.x;
    const int wave = tid >> 6;
    const int lane = tid & 63;

    __shared__ float sm;
    __shared__ float ssum[4];
    __shared__ float stot;

    if (tid == 0) {
        float m = blockmax[n * NCHUNK];
        #pragma unroll
        for (int i = 1; i < NCHUNK; ++i) m = fmaxf(m, blockmax[n * NCHUNK + i]);
        sm = m;
    }
    __syncthreads();
    const float m = sm;

    float4* row = (float4*)(att + (size_t)n * T_DIM);   // 1024 float4
    float4 vals[4];
    float sum = 0.f;
    #pragma unroll
    for (int i = 0; i < 4; ++i) {
        float4 v = row[tid + i * 256];
        v.x = __expf(v.x - m);
        v.y = __expf(v.y - m);
        v.z = __expf(v.z - m);
        v.w = __expf(v.w - m);
        sum += v.x + v.y + v.z + v.w;
        vals[i] = v;
    }
    // block reduce sum
    sum += __shfl_xor(sum, 1);
    sum += __shfl_xor(sum, 2);
    sum += __shfl_xor(sum, 4);
    sum += __shfl_xor(sum, 8);
    sum += __shfl_xor(sum, 16);
    sum += __shfl_xor(sum, 32);
    if (lane == 0) ssum[wave] = sum;
    __syncthreads();
    if (tid == 0) stot = ssum[0] + ssum[1] + ssum[2] + ssum[3];
    __syncthreads();
    const float inv = 1.0f / stot;

    #pragma unroll
    for (int i = 0; i < 4; ++i) {
        float4 v = vals[i];
        v.x *= inv; v.y *= inv; v.z *= inv; v.w *= inv;
        row[tid + i * 256] = v;
    }
}

// ---------------------------------------------------------------------------
// K3: partial PV. Grid N*NCHUNK blocks, 256 threads = (d:128, half:2).
// Skips t >= len entirely (value not read). Partials into ws.
// ---------------------------------------------------------------------------
__global__ __launch_bounds__(256) void pv_kernel(
    const float* __restrict__ att,     // normalized (N,T)
    const float* __restrict__ value,   // (T,N,D)
    const int*   __restrict__ lens,
    float*       __restrict__ partial) // (N,NCHUNK,D)
{
    const int b    = blockIdx.x;
    const int n    = b & (N_DIM - 1);
    const int c    = b >> 7;
    const int t0   = c * CHUNK;
    const int len  = lens[n];
    const int tid  = threadIdx.x;
    const int d    = tid & (D_DIM - 1);
    const int half = tid >> 7;

    if (t0 >= len) {
        if (tid < D_DIM)
            partial[((size_t)n * NCHUNK + c) * D_DIM + tid] = 0.0f;
        return;
    }

    const int tend = min(t0 + CHUNK, len);
    float acc = 0.f;
    #pragma unroll 4
    for (int t = t0 + half; t < tend; t += 2) {
        const float a = att[(size_t)n * T_DIM + t];
        acc += a * value[(size_t)t * (N_DIM * D_DIM) + n * D_DIM + d];
    }

    __shared__ float buf[256];
    buf[tid] = acc;
    __syncthreads();
    if (tid < D_DIM) {
        partial[((size_t)n * NCHUNK + c) * D_DIM + tid] =
            buf[tid] + buf[tid + D_DIM];
    }
}

// ---------------------------------------------------------------------------
// K4: reduce partials over chunks -> out (N,D).
// ---------------------------------------------------------------------------
__global__ __launch_bounds__(256) void reduce_kernel(
    const float* __restrict__ partial,  // (N,NCHUNK,D)
    float*       __restrict__ out)      // (N,D)
{
    const int idx = blockIdx.x * 256 + threadIdx.x;  // over N*D
    const int n = idx >> 7;
    const int d = idx & (D_DIM - 1);
    float s = 0.f;
    #pragma unroll
    for (int c = 0; c < NCHUNK; ++c)
        s += partial[((size_t)n * NCHUNK + c) * D_DIM + d];
    out[idx] = s;
}

extern "C" void kernel_launch(void* const* d_in, const int* in_sizes, int n_in,
                              void* d_out, int out_size, void* d_ws, size_t ws_size,
                              hipStream_t stream) {
    const float* q     = (const float*)d_in[0];   // (N,D)
    const float* key   = (const float*)d_in[1];   // (T,N,D)
    const float* value = (const float*)d_in[2];   // (T,N,D)
    const int*   lens  = (const int*)d_in[3];     // (N,)

    float* out = (float*)d_out;                   // first N*D floats
    float* att = out + N_DIM * D_DIM;             // next N*T floats

    float* blockmax = (float*)d_ws;                          // N*NCHUNK floats (8 KB)
    float* partial  = (float*)((char*)d_ws + 8192);          // N*NCHUNK*D floats (1 MB)

    energy_kernel <<<N_DIM * NCHUNK, 256, 0, stream>>>(q, key, lens, att, blockmax);
    softmax_kernel<<<N_DIM,          256, 0, stream>>>(att, blockmax);
    pv_kernel     <<<N_DIM * NCHUNK, 256, 0, stream>>>(att, value, lens, partial);
    reduce_kernel <<<(N_DIM * D_DIM) / 256, 256, 0, stream>>>(partial, out);
}

// Round 2
// 479.932 us; speedup vs baseline: 1.0080x; 1.0080x over previous
//
#include <hip/hip_runtime.h>

#define T_DIM 4096
#define N_DIM 128
#define D_DIM 128
#define CHUNK 256
#define NCHUNK (T_DIM / CHUNK)   // 16
#define NEGE (-1.0e9f)

// ---------------------------------------------------------------------------
// K1: energy[n,t] = dot(key[t,n,:], q[n,:]); masked t -> NEGE (key not read).
// Grid: N_DIM * NCHUNK blocks, 256 threads. Writes raw energy into att region
// of d_out and per-(n,chunk) max into ws.
// ---------------------------------------------------------------------------
__global__ __launch_bounds__(256) void energy_kernel(
    const float* __restrict__ q,      // (N,D)
    const float* __restrict__ key,    // (T,N,D)
    const int*   __restrict__ lens,   // (N)
    float*       __restrict__ att,    // (N,T)
    float*       __restrict__ blockmax) // (N,NCHUNK)
{
    const int b    = blockIdx.x;
    const int n    = b & (N_DIM - 1);
    const int c    = b >> 7;            // b / N_DIM
    const int t0   = c * CHUNK;
    const int len  = lens[n];
    const int tid  = threadIdx.x;

    // Fast path: whole chunk masked -> write NEGE, no key reads.
    if (t0 >= len) {
        att[(size_t)n * T_DIM + t0 + tid] = NEGE;
        if (tid == 0) blockmax[n * NCHUNK + c] = NEGE;
        return;
    }

    const int wave = tid >> 6;          // 0..3
    const int lane = tid & 63;
    const int half = lane >> 5;         // 0/1 (each half owns one t)
    const int l32  = lane & 31;

    // q fragment: float4 at d = l32*4 (covers all 128 d across 32 lanes)
    const float4 qv = *(const float4*)(q + n * D_DIM + l32 * 4);

    float lmax = NEGE;

    // Wave handles t pairs: t = t0 + wave*2 + i*8 + half, i in [0,32)
    #pragma unroll 4
    for (int i = 0; i < CHUNK / 8; ++i) {
        const int t = t0 + wave * 2 + i * 8 + half;
        float e;
        if (t < len) {   // uniform per 32-lane half
            const float4 kv = *(const float4*)(key + (size_t)t * (N_DIM * D_DIM)
                                               + n * D_DIM + l32 * 4);
            float p = kv.x * qv.x + kv.y * qv.y + kv.z * qv.z + kv.w * qv.w;
            p += __shfl_xor(p, 1);
            p += __shfl_xor(p, 2);
            p += __shfl_xor(p, 4);
            p += __shfl_xor(p, 8);
            p += __shfl_xor(p, 16);
            e = p;
        } else {
            e = NEGE;
        }
        if (l32 == 0) att[(size_t)n * T_DIM + t] = e;
        lmax = fmaxf(lmax, e);
    }

    // lmax is uniform within each half; combine halves, then across waves.
    lmax = fmaxf(lmax, __shfl_xor(lmax, 32));
    __shared__ float smax[4];
    if (lane == 0) smax[wave] = lmax;
    __syncthreads();
    if (tid == 0) {
        blockmax[n * NCHUNK + c] =
            fmaxf(fmaxf(smax[0], smax[1]), fmaxf(smax[2], smax[3]));
    }
}

// ---------------------------------------------------------------------------
// K2: per-row softmax + zero-init of out. One block per n, 256 threads;
// 16 floats/thread kept in registers between the exp pass and normalize pass.
// ---------------------------------------------------------------------------
__global__ __launch_bounds__(256) void softmax_kernel(
    float* __restrict__ att,              // (N,T)
    const float* __restrict__ blockmax,   // (N,NCHUNK)
    float* __restrict__ out)              // (N,D) -- zero-initialized here
{
    const int n   = blockIdx.x;
    const int tid = threadIdx.x;
    const int wave = tid >> 6;
    const int lane = tid & 63;

    __shared__ float smaxarr[NCHUNK];
    __shared__ float ssum[4];
    __shared__ float stot;

    if (tid < NCHUNK) smaxarr[tid] = blockmax[n * NCHUNK + tid];
    // zero the out row for K3's atomics (32 float4 = 128 floats)
    if (tid < 32) ((float4*)(out + n * D_DIM))[tid] = make_float4(0.f, 0.f, 0.f, 0.f);
    __syncthreads();
    float m = smaxarr[0];
    #pragma unroll
    for (int i = 1; i < NCHUNK; ++i) m = fmaxf(m, smaxarr[i]);

    float4* row = (float4*)(att + (size_t)n * T_DIM);   // 1024 float4
    float4 vals[4];
    float sum = 0.f;
    #pragma unroll
    for (int i = 0; i < 4; ++i) {
        float4 v = row[tid + i * 256];
        v.x = __expf(v.x - m);
        v.y = __expf(v.y - m);
        v.z = __expf(v.z - m);
        v.w = __expf(v.w - m);
        sum += v.x + v.y + v.z + v.w;
        vals[i] = v;
    }
    // block reduce sum
    sum += __shfl_xor(sum, 1);
    sum += __shfl_xor(sum, 2);
    sum += __shfl_xor(sum, 4);
    sum += __shfl_xor(sum, 8);
    sum += __shfl_xor(sum, 16);
    sum += __shfl_xor(sum, 32);
    if (lane == 0) ssum[wave] = sum;
    __syncthreads();
    if (tid == 0) stot = ssum[0] + ssum[1] + ssum[2] + ssum[3];
    __syncthreads();
    const float inv = 1.0f / stot;

    #pragma unroll
    for (int i = 0; i < 4; ++i) {
        float4 v = vals[i];
        v.x *= inv; v.y *= inv; v.z *= inv; v.w *= inv;
        row[tid + i * 256] = v;
    }
}

// ---------------------------------------------------------------------------
// K3: PV with float4 value loads (1 KB per wave instruction) + atomicAdd into
// out. Grid N*NCHUNK blocks, 256 threads = (d-quad:32, t-group:8).
// Fully-masked chunks return immediately (value not read, nothing written).
// ---------------------------------------------------------------------------
__global__ __launch_bounds__(256) void pv_kernel(
    const float* __restrict__ att,     // normalized (N,T)
    const float* __restrict__ value,   // (T,N,D)
    const int*   __restrict__ lens,
    float*       __restrict__ out)     // (N,D), pre-zeroed by K2
{
    const int b    = blockIdx.x;
    const int n    = b & (N_DIM - 1);
    const int c    = b >> 7;
    const int t0   = c * CHUNK;
    const int len  = lens[n];

    if (t0 >= len) return;   // contributes exactly zero

    const int tid  = threadIdx.x;
    const int qd   = tid & 31;     // d-quad index: d = qd*4
    const int g    = tid >> 5;     // t-group 0..7
    const int tend = min(t0 + CHUNK, len);

    float4 acc = make_float4(0.f, 0.f, 0.f, 0.f);
    #pragma unroll 4
    for (int t = t0 + g; t < tend; t += 8) {
        const float a = att[(size_t)n * T_DIM + t];
        const float4 v = *(const float4*)(value + (size_t)t * (N_DIM * D_DIM)
                                          + n * D_DIM + qd * 4);
        acc.x += a * v.x;
        acc.y += a * v.y;
        acc.z += a * v.z;
        acc.w += a * v.w;
    }

    // Reduce across the 8 t-groups (layout buf[g*32 + qd]).
    __shared__ float4 buf[256];
    buf[tid] = acc;
    __syncthreads();
    if (tid < 128) {
        float4 o = buf[tid + 128];
        buf[tid].x += o.x; buf[tid].y += o.y; buf[tid].z += o.z; buf[tid].w += o.w;
    }
    __syncthreads();
    if (tid < 64) {
        float4 o = buf[tid + 64];
        buf[tid].x += o.x; buf[tid].y += o.y; buf[tid].z += o.z; buf[tid].w += o.w;
    }
    __syncthreads();
    if (tid < 32) {
        float4 a0 = buf[tid];
        float4 a1 = buf[tid + 32];
        float* dst = out + n * D_DIM + tid * 4;
        atomicAdd(dst + 0, a0.x + a1.x);
        atomicAdd(dst + 1, a0.y + a1.y);
        atomicAdd(dst + 2, a0.z + a1.z);
        atomicAdd(dst + 3, a0.w + a1.w);
    }
}

extern "C" void kernel_launch(void* const* d_in, const int* in_sizes, int n_in,
                              void* d_out, int out_size, void* d_ws, size_t ws_size,
                              hipStream_t stream) {
    const float* q     = (const float*)d_in[0];   // (N,D)
    const float* key   = (const float*)d_in[1];   // (T,N,D)
    const float* value = (const float*)d_in[2];   // (T,N,D)
    const int*   lens  = (const int*)d_in[3];     // (N,)

    float* out = (float*)d_out;                   // first N*D floats
    float* att = out + N_DIM * D_DIM;             // next N*T floats

    float* blockmax = (float*)d_ws;               // N*NCHUNK floats (8 KB)

    energy_kernel <<<N_DIM * NCHUNK, 256, 0, stream>>>(q, key, lens, att, blockmax);
    softmax_kernel<<<N_DIM,          256, 0, stream>>>(att, blockmax, out);
    pv_kernel     <<<N_DIM * NCHUNK, 256, 0, stream>>>(att, value, lens, out);
}

// Round 3
// 477.102 us; speedup vs baseline: 1.0140x; 1.0059x over previous
//
#include <hip/hip_runtime.h>

#define T_DIM 4096
#define N_DIM 128
#define D_DIM 128
#define CHUNK 256
#define NCHUNK (T_DIM / CHUNK)   // 16
#define NEGE (-1.0e9f)

// ---------------------------------------------------------------------------
// K1: energy[n,t] = dot(key[t,n,:], q[n,:]); masked t -> NEGE (key not read).
// Also emits per-chunk max m_c and per-chunk expsum s_c = sum exp(e - m_c)
// (energies held in 32 VGPRs for the second pass). c==0 blocks zero out[n,:]
// for K2's atomics. Grid: N_DIM * NCHUNK blocks, 256 threads.
// ---------------------------------------------------------------------------
__global__ __launch_bounds__(256) void energy_kernel(
    const float* __restrict__ q,        // (N,D)
    const float* __restrict__ key,      // (T,N,D)
    const int*   __restrict__ lens,     // (N)
    float*       __restrict__ att,      // (N,T) raw energies
    float*       __restrict__ blockmax, // (N,NCHUNK)
    float*       __restrict__ blocksum, // (N,NCHUNK)
    float*       __restrict__ out)      // (N,D) zeroed here (c==0 blocks)
{
    const int b    = blockIdx.x;
    const int n    = b & (N_DIM - 1);
    const int c    = b >> 7;            // b / N_DIM
    const int t0   = c * CHUNK;
    const int len  = lens[n];
    const int tid  = threadIdx.x;

    // Fast path: whole chunk masked -> vector-write NEGE, no key reads.
    if (t0 >= len) {
        if (tid < 64)
            ((float4*)(att + (size_t)n * T_DIM + t0))[tid] =
                make_float4(NEGE, NEGE, NEGE, NEGE);
        if (tid == 0) {
            blockmax[n * NCHUNK + c] = NEGE;
            blocksum[n * NCHUNK + c] = 0.0f;
        }
        return;
    }

    // c==0 is never fully masked (len >= 1): zero the out row for K2 atomics.
    if (c == 0 && tid < 32)
        ((float4*)(out + n * D_DIM))[tid] = make_float4(0.f, 0.f, 0.f, 0.f);

    const int wave = tid >> 6;          // 0..3
    const int lane = tid & 63;
    const int half = lane >> 5;         // 0/1 (each half owns one t)
    const int l32  = lane & 31;

    // q fragment: float4 at d = l32*4 (covers all 128 d across 32 lanes)
    const float4 qv = *(const float4*)(q + n * D_DIM + l32 * 4);

    float evals[CHUNK / 8];             // 32 energies per lane (uniform per half)
    float lmax = NEGE;

    // Wave handles t pairs: t = t0 + wave*2 + i*8 + half, i in [0,32)
    #pragma unroll
    for (int i = 0; i < CHUNK / 8; ++i) {
        const int t = t0 + wave * 2 + i * 8 + half;
        float e;
        if (t < len) {   // uniform per 32-lane half
            const float4 kv = *(const float4*)(key + (size_t)t * (N_DIM * D_DIM)
                                               + n * D_DIM + l32 * 4);
            float p = kv.x * qv.x + kv.y * qv.y + kv.z * qv.z + kv.w * qv.w;
            p += __shfl_xor(p, 1);
            p += __shfl_xor(p, 2);
            p += __shfl_xor(p, 4);
            p += __shfl_xor(p, 8);
            p += __shfl_xor(p, 16);
            e = p;
        } else {
            e = NEGE;
        }
        if (l32 == 0) att[(size_t)n * T_DIM + t] = e;
        evals[i] = e;
        lmax = fmaxf(lmax, e);
    }

    // Block max (broadcast to all threads).
    lmax = fmaxf(lmax, __shfl_xor(lmax, 32));
    __shared__ float smax[4];
    __shared__ float ssum[4];
    if (lane == 0) smax[wave] = lmax;
    __syncthreads();
    const float m = fmaxf(fmaxf(smax[0], smax[1]), fmaxf(smax[2], smax[3]));

    // Per-chunk expsum. Lane-local sum already covers its half's 32 t's
    // (values uniform within half); add the other half, then across waves.
    float s = 0.f;
    #pragma unroll
    for (int i = 0; i < CHUNK / 8; ++i) s += __expf(evals[i] - m);
    s += __shfl_xor(s, 32);
    if (lane == 0) ssum[wave] = s;
    __syncthreads();
    if (tid == 0) {
        blockmax[n * NCHUNK + c] = m;
        blocksum[n * NCHUNK + c] = ssum[0] + ssum[1] + ssum[2] + ssum[3];
    }
}

// ---------------------------------------------------------------------------
// K2: fused softmax-normalize + PV. Per (n,c) block: rebuild global (m, Z)
// from the 16 chunk stats, normalize this att chunk in one R-M-W (p stashed
// in LDS), then accumulate p·value with float4 loads and atomicAdd into out.
// Fully-masked chunks just zero their att chunk (value not read).
// ---------------------------------------------------------------------------
__global__ __launch_bounds__(256) void pv_kernel(
    float*       __restrict__ att,      // (N,T): raw in, normalized out
    const float* __restrict__ value,    // (T,N,D)
    const int*   __restrict__ lens,
    const float* __restrict__ blockmax, // (N,NCHUNK)
    const float* __restrict__ blocksum, // (N,NCHUNK)
    float*       __restrict__ out)      // (N,D), zeroed by K1
{
    const int b    = blockIdx.x;
    const int n    = b & (N_DIM - 1);
    const int c    = b >> 7;
    const int t0   = c * CHUNK;
    const int len  = lens[n];
    const int tid  = threadIdx.x;

    if (t0 >= len) {
        // p = 0 exactly for masked positions; att currently NEGE -> overwrite.
        if (tid < 64)
            ((float4*)(att + (size_t)n * T_DIM + t0))[tid] =
                make_float4(0.f, 0.f, 0.f, 0.f);
        return;
    }

    __shared__ float sm[NCHUNK], ss[NCHUNK];
    __shared__ float sp[CHUNK];          // normalized p for this chunk
    if (tid < NCHUNK) {
        sm[tid] = blockmax[n * NCHUNK + tid];
        ss[tid] = blocksum[n * NCHUNK + tid];
    }
    __syncthreads();

    float m = sm[0];
    #pragma unroll
    for (int i = 1; i < NCHUNK; ++i) m = fmaxf(m, sm[i]);
    float Z = 0.f;
    #pragma unroll
    for (int i = 0; i < NCHUNK; ++i) Z += ss[i] * __expf(sm[i] - m);
    const float inv = 1.0f / Z;

    // Phase A: normalize att chunk (float4), stash p in LDS.
    if (tid < 64) {
        float4* arow = (float4*)(att + (size_t)n * T_DIM + t0);
        float4 e4 = arow[tid];
        float4 p4;
        p4.x = __expf(e4.x - m) * inv;   // exp(NEGE-m)=0 -> masked tail exact 0
        p4.y = __expf(e4.y - m) * inv;
        p4.z = __expf(e4.z - m) * inv;
        p4.w = __expf(e4.w - m) * inv;
        arow[tid] = p4;
        ((float4*)sp)[tid] = p4;
    }
    __syncthreads();

    // Phase B: PV. threads = (d-quad qd:32, t-group g:8); float4 value loads.
    const int qd   = tid & 31;
    const int g    = tid >> 5;
    const int tend = min(t0 + CHUNK, len);

    float4 acc = make_float4(0.f, 0.f, 0.f, 0.f);
    #pragma unroll 4
    for (int t = t0 + g; t < tend; t += 8) {
        const float a = sp[t - t0];
        const float4 v = *(const float4*)(value + (size_t)t * (N_DIM * D_DIM)
                                          + n * D_DIM + qd * 4);
        acc.x += a * v.x;
        acc.y += a * v.y;
        acc.z += a * v.z;
        acc.w += a * v.w;
    }

    __shared__ float4 buf[256];
    buf[tid] = acc;
    __syncthreads();
    if (tid < 128) {
        float4 o = buf[tid + 128];
        buf[tid].x += o.x; buf[tid].y += o.y; buf[tid].z += o.z; buf[tid].w += o.w;
    }
    __syncthreads();
    if (tid < 64) {
        float4 o = buf[tid + 64];
        buf[tid].x += o.x; buf[tid].y += o.y; buf[tid].z += o.z; buf[tid].w += o.w;
    }
    __syncthreads();
    if (tid < 32) {
        float4 a0 = buf[tid];
        float4 a1 = buf[tid + 32];
        float* dst = out + n * D_DIM + tid * 4;
        atomicAdd(dst + 0, a0.x + a1.x);
        atomicAdd(dst + 1, a0.y + a1.y);
        atomicAdd(dst + 2, a0.z + a1.z);
        atomicAdd(dst + 3, a0.w + a1.w);
    }
}

extern "C" void kernel_launch(void* const* d_in, const int* in_sizes, int n_in,
                              void* d_out, int out_size, void* d_ws, size_t ws_size,
                              hipStream_t stream) {
    const float* q     = (const float*)d_in[0];   // (N,D)
    const float* key   = (const float*)d_in[1];   // (T,N,D)
    const float* value = (const float*)d_in[2];   // (T,N,D)
    const int*   lens  = (const int*)d_in[3];     // (N,)

    float* out = (float*)d_out;                   // first N*D floats
    float* att = out + N_DIM * D_DIM;             // next N*T floats

    float* blockmax = (float*)d_ws;                       // N*NCHUNK floats
    float* blocksum = (float*)((char*)d_ws + 8192);       // N*NCHUNK floats

    energy_kernel<<<N_DIM * NCHUNK, 256, 0, stream>>>(q, key, lens, att,
                                                      blockmax, blocksum, out);
    pv_kernel    <<<N_DIM * NCHUNK, 256, 0, stream>>>(att, value, lens,
                                                      blockmax, blocksum, out);
}